// Round 4
// baseline (145.655 us; speedup 1.0000x reference)
//
#include <hip/hip_runtime.h>

#ifndef __has_builtin
#define __has_builtin(x) 0
#endif

#if __has_builtin(__builtin_amdgcn_exp2f)
#define EXP2F(x) __builtin_amdgcn_exp2f(x)
#else
#define EXP2F(x) exp2f(x)
#endif

#if __has_builtin(__builtin_amdgcn_rcpf)
#define RCPF(x) __builtin_amdgcn_rcpf(x)
#else
#define RCPF(x) (1.0f / (x))
#endif

namespace {

constexpr int kB = 65536;
constexpr int kT = 50;
constexpr int kI = 2;
constexpr int kH = 20;
constexpr int kO = 2;
constexpr int kCT = 4;          // steps per staged chunk
constexpr int kNC = 12;         // full chunks (48 steps); tail = 2 steps
constexpr int kQS = 84;         // floats per quad LDS slice (80 + 4 pad, 16B-aligned)
constexpr int kGB = 64;         // batch elements (quads) per block

__device__ __forceinline__ float fast_tanh(float v) {
    const float p = EXP2F(v * 2.8853900817779268f);
    return fmaf(-2.0f, RCPF(p + 1.0f), 1.0f);
}

// Intra-quad lane exchange via DPP quad_perm (pure VALU, no DS latency).
// xor1: [1,0,3,2]=0xB1  xor2: [2,3,0,1]=0x4E  xor3: [3,2,1,0]=0x1B
#if __has_builtin(__builtin_amdgcn_mov_dpp)
template <int CTRL>
__device__ __forceinline__ float fqp(float v) {
    return __int_as_float(
        __builtin_amdgcn_mov_dpp(__float_as_int(v), CTRL, 0xF, 0xF, true));
}
#else
template <int CTRL>
__device__ __forceinline__ float fqp(float v) {
    constexpr int d = (CTRL == 0xB1) ? 1 : (CTRL == 0x4E) ? 2 : 3;
    return __shfl_xor(v, d);
}
#endif

// 4 threads (one quad) per batch element; thread sub owns hidden rows 4*i+sub.
// W_hh in registers, columns permuted for DPP gather (proven in R1/R2):
//   w[i][r][d] = W_hh[(4i+sub)*20 + (4r + (sub^d))]
// Mask pipeline (wave-local, ZERO barriers): lane loads 20 contiguous floats
// (5 x dwordx4, 320B/quad burst) one chunk ahead into regs, ds_writes them
// into a quad-private LDS slice, consumes via ds_read_b32. Same-wave DS ops
// execute in order -> no sync needed.
__global__ __launch_bounds__(256)
__attribute__((amdgpu_waves_per_eu(2)))
void dprnn_kernel(
    const float* __restrict__ x, const float* __restrict__ W_ih,
    const float* __restrict__ W_hh, const float* __restrict__ b_ih,
    const float* __restrict__ b_hh, const float* __restrict__ W_out,
    const float* __restrict__ b_out, const float* __restrict__ mask,
    float* __restrict__ out)
{
    __shared__ __align__(16) float sm[kGB * kQS + kGB * kT * kO];  // 47104 B
    float* lds_m = sm;                  // [64][84]
    float* lds_o = sm + kGB * kQS;      // [64][100]

    const int tidx = threadIdx.x;
    const int gl   = tidx >> 2;         // local elem / quad index 0..63
    const int sub  = tidx & 3;          // quarter of H owned
    const size_t g = (size_t)blockIdx.x * kGB + gl;

    // ---- weights into registers (column-permuted for DPP gather) ----
    float w[5][5][4];
    float wi0[5], wi1[5], bia[5], wo0[5], wo1[5];
#pragma unroll
    for (int i = 0; i < 5; ++i) {
        const int row = 4 * i + sub;
#pragma unroll
        for (int r = 0; r < 5; ++r)
#pragma unroll
            for (int d = 0; d < 4; ++d)
                w[i][r][d] = W_hh[row * kH + 4 * r + (sub ^ d)];
        wi0[i] = W_ih[row * kI + 0];
        wi1[i] = W_ih[row * kI + 1];
        bia[i] = b_ih[row] + b_hh[row];
        wo0[i] = W_out[row];
        wo1[i] = W_out[kH + row];
    }
    const float bo0 = b_out[0];
    const float bo1 = b_out[1];

    // ---- addressing ----
    const float* msrc = mask + g * (kT * kH) + sub * 20;  // lane's 80B chunk slice
    const float* mrow = mask + g * (kT * kH) + sub;       // tail scatter base
    const float* xsrc = x + g * (kT * kI);
    const int wbase = gl * kQS + sub * 20;                // LDS write base (floats)
    const int rbase = gl * kQS + sub;                     // LDS read base

    float4 f[5];            // in-flight mask chunk (one chunk ahead)
    float4 xF[2], xA[2];    // in-flight / active x (8 floats = 4 steps)
    float m48[5], m49[5];   // tail masks

    auto load_chunk = [&](int c) {
#pragma unroll
        for (int j = 0; j < 5; ++j)
            f[j] = *(const float4*)(msrc + c * 80 + 4 * j);
        xF[0] = *(const float4*)(xsrc + c * 8);
        xF[1] = *(const float4*)(xsrc + c * 8 + 4);
    };
    auto write_chunk = [&]() {
#pragma unroll
        for (int j = 0; j < 5; ++j)
            *(float4*)&lds_m[wbase + 4 * j] = f[j];
    };

    float h[5] = {0.f, 0.f, 0.f, 0.f, 0.f};

    // one RNN step (math identical to R2's proven path)
    auto core = [&](const float m[5], float x0, float x1, int t) {
        float acc[5];
#pragma unroll
        for (int i = 0; i < 5; ++i)
            acc[i] = fmaf(wi0[i], x0, fmaf(wi1[i], x1, bia[i]));
#pragma unroll
        for (int r = 0; r < 5; ++r) {
            const float v0 = h[r];
            const float v1 = fqp<0xB1>(h[r]);
            const float v2 = fqp<0x4E>(h[r]);
            const float v3 = fqp<0x1B>(h[r]);
#pragma unroll
            for (int i = 0; i < 5; ++i) {
                acc[i] = fmaf(w[i][r][0], v0, acc[i]);
                acc[i] = fmaf(w[i][r][1], v1, acc[i]);
                acc[i] = fmaf(w[i][r][2], v2, acc[i]);
                acc[i] = fmaf(w[i][r][3], v3, acc[i]);
            }
        }
        float p0 = 0.f, p1 = 0.f;
#pragma unroll
        for (int i = 0; i < 5; ++i) {
            const float hn = fast_tanh(acc[i]);
            h[i] = hn;
            const float dm = hn * m[i];
            p0 = fmaf(dm, wo0[i], p0);
            p1 = fmaf(dm, wo1[i], p1);
        }
        p0 += fqp<0xB1>(p0);
        p0 += fqp<0x4E>(p0);
        p1 += fqp<0xB1>(p1);
        p1 += fqp<0x4E>(p1);
        if (sub == 0)
            *(float2*)&lds_o[gl * (kT * kO) + t * kO] =
                make_float2(p0 + bo0, p1 + bo1);
    };

    // ---- prologue: chunk 0 staged, chunk 1 in flight ----
    load_chunk(0);
    write_chunk();                 // vmcnt wait on f inserted by compiler
    xA[0] = xF[0]; xA[1] = xF[1];
    load_chunk(1);

#pragma unroll 1
    for (int c = 0; c < kNC; ++c) {
#pragma unroll
        for (int s = 0; s < kCT; ++s) {
            float m[5];
#pragma unroll
            for (int r = 0; r < 5; ++r)
                m[r] = lds_m[rbase + s * kH + 4 * r];
            const float x0 = (s == 0) ? xA[0].x : (s == 1) ? xA[0].z
                            : (s == 2) ? xA[1].x : xA[1].z;
            const float x1 = (s == 0) ? xA[0].y : (s == 1) ? xA[0].w
                            : (s == 2) ? xA[1].y : xA[1].w;
            core(m, x0, x1, c * kCT + s);
        }
        if (c < kNC - 1) {
            // chunk c fully consumed (same-wave DS ordering) -> overwrite
            write_chunk();                       // stages chunk c+1
            xA[0] = xF[0]; xA[1] = xF[1];
            if (c < kNC - 2) {
                load_chunk(c + 2);
            } else {
                // prefetch tail (t = 48, 49) masks + x
#pragma unroll
                for (int r = 0; r < 5; ++r) {
                    m48[r] = mrow[48 * kH + 4 * r];
                    m49[r] = mrow[49 * kH + 4 * r];
                }
                xF[0] = *(const float4*)(xsrc + 96);
            }
        }
    }
    // tail steps
    core(m48, xF[0].x, xF[0].y, 48);
    core(m49, xF[0].z, xF[0].w, 49);

    // ---- coalesced writeback of this block's 64*100 floats ----
    __syncthreads();
    float* ob = out + (size_t)blockIdx.x * (kGB * kT * kO);
#pragma unroll
    for (int it = 0; it < 6; ++it) {
        const int idx = it * 1024 + tidx * 4;
        const float4 v = *(const float4*)&lds_o[idx];
        *(float4*)(ob + idx) = v;
    }
    {
        const int idx = 6144 + tidx;
        ob[idx] = lds_o[idx];
    }
}

}  // namespace

extern "C" void kernel_launch(void* const* d_in, const int* in_sizes, int n_in,
                              void* d_out, int out_size, void* d_ws, size_t ws_size,
                              hipStream_t stream) {
    const float* x     = (const float*)d_in[0];
    const float* W_ih  = (const float*)d_in[1];
    const float* W_hh  = (const float*)d_in[2];
    const float* b_ih  = (const float*)d_in[3];
    const float* b_hh  = (const float*)d_in[4];
    const float* W_out = (const float*)d_in[5];
    const float* b_out = (const float*)d_in[6];
    const float* mask  = (const float*)d_in[7];
    float* out = (float*)d_out;

    dim3 block(256);
    dim3 grid(kB / kGB);                 // 1024 blocks
    dprnn_kernel<<<grid, block, 0, stream>>>(x, W_ih, W_hh, b_ih, b_hh,
                                             W_out, b_out, mask, out);
}

// Round 5
// 89.411 us; speedup vs baseline: 1.6290x; 1.6290x over previous
//
#include <hip/hip_runtime.h>

#ifndef __has_builtin
#define __has_builtin(x) 0
#endif

#if __has_builtin(__builtin_amdgcn_exp2f)
#define EXP2F(x) __builtin_amdgcn_exp2f(x)
#else
#define EXP2F(x) exp2f(x)
#endif

#if __has_builtin(__builtin_amdgcn_rcpf)
#define RCPF(x) __builtin_amdgcn_rcpf(x)
#else
#define RCPF(x) (1.0f / (x))
#endif

namespace {

constexpr int kB = 65536;
constexpr int kT = 50;
constexpr int kI = 2;
constexpr int kH = 20;
constexpr int kO = 2;
constexpr int kGB = 128;   // batch elements per block (64 quads x 2 elems)

__device__ __forceinline__ float fast_tanh(float v) {
    // tanh(v) = 1 - 2/(exp(2v)+1); v_exp_f32 saturates so no clamp needed
    const float p = EXP2F(v * 2.8853900817779268f);
    return fmaf(-2.0f, RCPF(p + 1.0f), 1.0f);
}

// Intra-quad lane exchange via DPP quad_perm (pure VALU, no DS latency).
// xor1: [1,0,3,2]=0xB1  xor2: [2,3,0,1]=0x4E  xor3: [3,2,1,0]=0x1B
#if __has_builtin(__builtin_amdgcn_mov_dpp)
template <int CTRL>
__device__ __forceinline__ float fqp(float v) {
    return __int_as_float(
        __builtin_amdgcn_mov_dpp(__float_as_int(v), CTRL, 0xF, 0xF, true));
}
#else
template <int CTRL>
__device__ __forceinline__ float fqp(float v) {
    constexpr int d = (CTRL == 0xB1) ? 1 : (CTRL == 0x4E) ? 2 : 3;
    return __shfl_xor(v, d);
}
#endif

// 4 threads (one quad) per 2 batch elements; thread sub owns hidden rows
// 4*i+sub of BOTH elements. W_hh in registers ONCE, shared by both
// recurrences (columns permuted for DPP gather, proven R1/R2):
//   w[i][r][d] = W_hh[(4i+sub)*20 + (4r + (sub^d))]
// Two independent dependency chains per thread fill each other's stalls.
__global__ __launch_bounds__(256)
__attribute__((amdgpu_waves_per_eu(2, 2)))
void dprnn_kernel(
    const float* __restrict__ x, const float* __restrict__ W_ih,
    const float* __restrict__ W_hh, const float* __restrict__ b_ih,
    const float* __restrict__ b_hh, const float* __restrict__ W_out,
    const float* __restrict__ b_out, const float* __restrict__ mask,
    float* __restrict__ out)
{
    __shared__ __align__(16) float lds_o[kGB * kT * kO];  // 51200 B

    const int tidx = threadIdx.x;
    const int gl   = tidx >> 2;          // quad index 0..63
    const int sub  = tidx & 3;           // quarter of H owned
    const size_t gA = (size_t)blockIdx.x * kGB + gl;
    const size_t gB = gA + 64;

    // ---- weights into registers (shared by both elements) ----
    float w[5][5][4];
    float wi0[5], wi1[5], bia[5], wo0[5], wo1[5];
#pragma unroll
    for (int i = 0; i < 5; ++i) {
        const int row = 4 * i + sub;
#pragma unroll
        for (int r = 0; r < 5; ++r)
#pragma unroll
            for (int d = 0; d < 4; ++d)
                w[i][r][d] = W_hh[row * kH + 4 * r + (sub ^ d)];
        wi0[i] = W_ih[row * kI + 0];
        wi1[i] = W_ih[row * kI + 1];
        bia[i] = b_ih[row] + b_hh[row];
        wo0[i] = W_out[row];
        wo1[i] = W_out[kH + row];
    }
    const float bo0 = b_out[0];
    const float bo1 = b_out[1];

    float hA[5] = {0.f, 0.f, 0.f, 0.f, 0.f};
    float hB[5] = {0.f, 0.f, 0.f, 0.f, 0.f};

    const float* mpA = mask + gA * (kT * kH) + sub;
    const float* mpB = mask + gB * (kT * kH) + sub;
    const float* xpA = x + gA * (kT * kI);
    const float* xpB = x + gB * (kT * kI);

    // one timestep for BOTH elements (interleaved independent chains)
    auto step = [&](const float mA[5], const float mB[5],
                    float xa0, float xa1, float xb0, float xb1, int t) {
        float aA[5], aB[5];
#pragma unroll
        for (int i = 0; i < 5; ++i) {
            aA[i] = fmaf(wi0[i], xa0, fmaf(wi1[i], xa1, bia[i]));
            aB[i] = fmaf(wi0[i], xb0, fmaf(wi1[i], xb1, bia[i]));
        }
#pragma unroll
        for (int r = 0; r < 5; ++r) {
            const float vA0 = hA[r];
            const float vA1 = fqp<0xB1>(hA[r]);
            const float vA2 = fqp<0x4E>(hA[r]);
            const float vA3 = fqp<0x1B>(hA[r]);
            const float vB0 = hB[r];
            const float vB1 = fqp<0xB1>(hB[r]);
            const float vB2 = fqp<0x4E>(hB[r]);
            const float vB3 = fqp<0x1B>(hB[r]);
#pragma unroll
            for (int i = 0; i < 5; ++i) {
                aA[i] = fmaf(w[i][r][0], vA0, aA[i]);
                aB[i] = fmaf(w[i][r][0], vB0, aB[i]);
                aA[i] = fmaf(w[i][r][1], vA1, aA[i]);
                aB[i] = fmaf(w[i][r][1], vB1, aB[i]);
                aA[i] = fmaf(w[i][r][2], vA2, aA[i]);
                aB[i] = fmaf(w[i][r][2], vB2, aB[i]);
                aA[i] = fmaf(w[i][r][3], vA3, aA[i]);
                aB[i] = fmaf(w[i][r][3], vB3, aB[i]);
            }
        }
        float pA0 = 0.f, pA1 = 0.f, pB0 = 0.f, pB1 = 0.f;
#pragma unroll
        for (int i = 0; i < 5; ++i) {
            const float hnA = fast_tanh(aA[i]);
            const float hnB = fast_tanh(aB[i]);
            hA[i] = hnA;
            hB[i] = hnB;
            const float dA = hnA * mA[i];
            const float dB = hnB * mB[i];
            pA0 = fmaf(dA, wo0[i], pA0);
            pA1 = fmaf(dA, wo1[i], pA1);
            pB0 = fmaf(dB, wo0[i], pB0);
            pB1 = fmaf(dB, wo1[i], pB1);
        }
        pA0 += fqp<0xB1>(pA0); pA0 += fqp<0x4E>(pA0);
        pA1 += fqp<0xB1>(pA1); pA1 += fqp<0x4E>(pA1);
        pB0 += fqp<0xB1>(pB0); pB0 += fqp<0x4E>(pB0);
        pB1 += fqp<0xB1>(pB1); pB1 += fqp<0x4E>(pB1);
        if (sub == 0) {
            *(float2*)&lds_o[gl * (kT * kO) + t * kO] =
                make_float2(pA0 + bo0, pA1 + bo1);
            *(float2*)&lds_o[(gl + 64) * (kT * kO) + t * kO] =
                make_float2(pB0 + bo0, pB1 + bo1);
        }
    };

    // ---- prologue: masks for t=0,1 and x for t=0,1 ----
    float m0A[5], m1A[5], m0B[5], m1B[5];
#pragma unroll
    for (int r = 0; r < 5; ++r) {
        m0A[r] = mpA[0 * kH + 4 * r];
        m1A[r] = mpA[1 * kH + 4 * r];
        m0B[r] = mpB[0 * kH + 4 * r];
        m1B[r] = mpB[1 * kH + 4 * r];
    }
    float4 xqA = *(const float4*)xpA;
    float4 xqB = *(const float4*)xpB;

    // ---- main: 24 blocks of 2 steps with distance-2 prefetch ----
    for (int tb = 0; tb < kT - 2; tb += 2) {
        float n0A[5], n1A[5], n0B[5], n1B[5];
        const float* qA = mpA + (tb + 2) * kH;
        const float* qB = mpB + (tb + 2) * kH;
#pragma unroll
        for (int r = 0; r < 5; ++r) {
            n0A[r] = qA[4 * r];
            n1A[r] = qA[kH + 4 * r];
            n0B[r] = qB[4 * r];
            n1B[r] = qB[kH + 4 * r];
        }
        const float4 xnA = *(const float4*)(xpA + (tb + 2) * kI);
        const float4 xnB = *(const float4*)(xpB + (tb + 2) * kI);

        step(m0A, m0B, xqA.x, xqA.y, xqB.x, xqB.y, tb);
        step(m1A, m1B, xqA.z, xqA.w, xqB.z, xqB.w, tb + 1);

#pragma unroll
        for (int r = 0; r < 5; ++r) {
            m0A[r] = n0A[r]; m1A[r] = n1A[r];
            m0B[r] = n0B[r]; m1B[r] = n1B[r];
        }
        xqA = xnA;
        xqB = xnB;
    }
    // tail: t = 48, 49
    step(m0A, m0B, xqA.x, xqA.y, xqB.x, xqB.y, kT - 2);
    step(m1A, m1B, xqA.z, xqA.w, xqB.z, xqB.w, kT - 1);

    // ---- coalesced writeback of this block's 128*100 floats ----
    __syncthreads();
    float* ob = out + (size_t)blockIdx.x * (kGB * kT * kO);
#pragma unroll
    for (int it = 0; it < 12; ++it) {
        const int idx = it * 1024 + tidx * 4;
        const float4 v = *(const float4*)&lds_o[idx];
        *(float4*)(ob + idx) = v;
    }
    if (tidx < 128) {
        const int idx = 12288 + tidx * 4;
        const float4 v = *(const float4*)&lds_o[idx];
        *(float4*)(ob + idx) = v;
    }
}

}  // namespace

extern "C" void kernel_launch(void* const* d_in, const int* in_sizes, int n_in,
                              void* d_out, int out_size, void* d_ws, size_t ws_size,
                              hipStream_t stream) {
    const float* x     = (const float*)d_in[0];
    const float* W_ih  = (const float*)d_in[1];
    const float* W_hh  = (const float*)d_in[2];
    const float* b_ih  = (const float*)d_in[3];
    const float* b_hh  = (const float*)d_in[4];
    const float* W_out = (const float*)d_in[5];
    const float* b_out = (const float*)d_in[6];
    const float* mask  = (const float*)d_in[7];
    float* out = (float*)d_out;

    dim3 block(256);
    dim3 grid(kB / kGB);                 // 512 blocks
    dprnn_kernel<<<grid, block, 0, stream>>>(x, W_ih, W_hh, b_ih, b_hh,
                                             W_out, b_out, mask, out);
}